// Round 4
// baseline (58.534 us; speedup 1.0000x reference)
//
#include <hip/hip_runtime.h>

#define VEC_D   128
#define N_WORDS 100000
#define BATCH   16384
#define CTX     8
#define NS      16

typedef float f32x4 __attribute__((ext_vector_type(4)));
typedef int   i32x4 __attribute__((ext_vector_type(4)));

// ---------------------------------------------------------------------------
// Kernel 1: transpose outputs [128, N_WORDS] -> outT [N_WORDS, 128]
// Tile = 32 words x 128 d. N_WORDS = 3125 * 32 exactly (no bounds checks).
// Nontemporal f32x4 reads along words (read exactly once; keep L3 for outT),
// f32x4 writes along d. ~102 MB total; measured ~14 us (near floor).
// ---------------------------------------------------------------------------
__global__ __launch_bounds__(256) void transpose_kernel(
    const float* __restrict__ src,   // [128][N_WORDS]
    float* __restrict__ dst)         // [N_WORDS][128]
{
    __shared__ float lds[32][VEC_D + 1];
    const int tid = threadIdx.x;
    const int w0  = blockIdx.x * 32;

    #pragma unroll
    for (int p = 0; p < 4; ++p) {
        const int d = p * 32 + (tid >> 3);
        const int w = (tid & 7) * 4;
        const f32x4 v = __builtin_nontemporal_load(
            (const f32x4*)&src[(size_t)d * N_WORDS + w0 + w]);
        lds[w + 0][d] = v.x;
        lds[w + 1][d] = v.y;
        lds[w + 2][d] = v.z;
        lds[w + 3][d] = v.w;
    }
    __syncthreads();

    #pragma unroll
    for (int p = 0; p < 4; ++p) {
        const int wl = p * 8 + (tid >> 5);
        const int d4 = (tid & 31) * 4;
        f32x4 v;
        v.x = lds[wl][d4 + 0];
        v.y = lds[wl][d4 + 1];
        v.z = lds[wl][d4 + 2];
        v.w = lds[wl][d4 + 3];
        *(f32x4*)&dst[(size_t)(w0 + wl) * VEC_D + d4] = v;
    }
}

// ---------------------------------------------------------------------------
// Kernel 2: main compute. 32 lanes per batch row; lane r owns d = 4r..4r+3
// (one float4). 8192 waves -> 32 waves/CU grid-offered; launch_bounds(256,8)
// caps VGPR<=64 so occupancy stays 8 waves/SIMD. Gathers prefetched in
// explicit batches of 4 (forces >=4 loads in flight per lane). 16-shuffle
// butterfly fold over the 16-lane subgroup + one cross-subgroup add; lane r
// (r<16) ends holding sample brev4(r), summed over all 32 lanes.
// ---------------------------------------------------------------------------
template <bool TRANSPOSED>
__global__ __launch_bounds__(256, 8) void dm_kernel(
    const int*   __restrict__ doc_ids,
    const int*   __restrict__ context_ids,
    const int*   __restrict__ sample_ids,
    const float* __restrict__ pm,      // [N_DOCS][128]
    const float* __restrict__ wm,      // [N_WORDS][128]
    const float* __restrict__ outsrc,  // TRANSPOSED ? outT [N_WORDS][128] : outputs [128][N_WORDS]
    float*       __restrict__ out)     // [BATCH][NS]
{
    const int tid = threadIdx.x;
    const int r   = tid & 31;                    // lane within row-group
    const int b   = blockIdx.x * 8 + (tid >> 5); // 8 batch rows per block
    const int d0  = r * 4;

    // ---- input vector slice: pm[doc] + sum_c wm[ctx[c]] ----
    const int doc = doc_ids[b];
    f32x4 v = *(const f32x4*)&pm[(size_t)doc * VEC_D + d0];

    const i32x4* cid = (const i32x4*)&context_ids[b * CTX];
    #pragma unroll
    for (int g = 0; g < 2; ++g) {                // 2 batches of 4 ctx rows
        const i32x4 c4 = cid[g];
        f32x4 w[4];
        #pragma unroll
        for (int k = 0; k < 4; ++k)
            w[k] = *(const f32x4*)&wm[(size_t)c4[k] * VEC_D + d0];
        #pragma unroll
        for (int k = 0; k < 4; ++k)
            v += w[k];
    }

    // ---- 16 sample dots, gathers prefetched 4 at a time ----
    float acc[NS];
    const i32x4* sid = (const i32x4*)&sample_ids[b * NS];
    #pragma unroll
    for (int g = 0; g < 4; ++g) {                // 4 batches of 4 samples
        const i32x4 s4 = sid[g];
        if (TRANSPOSED) {
            f32x4 o[4];
            #pragma unroll
            for (int k = 0; k < 4; ++k)
                o[k] = *(const f32x4*)&outsrc[(size_t)s4[k] * VEC_D + d0];
            #pragma unroll
            for (int k = 0; k < 4; ++k)
                acc[g * 4 + k] = v.x * o[k].x + v.y * o[k].y
                               + v.z * o[k].z + v.w * o[k].w;
        } else {
            #pragma unroll
            for (int k = 0; k < 4; ++k) {
                float a = 0.0f;
                #pragma unroll
                for (int q = 0; q < 4; ++q)
                    a += v[q] * outsrc[(size_t)(d0 + q) * N_WORDS + s4[k]];
                acc[g * 4 + k] = a;
            }
        }
    }

    // ---- butterfly fold: 16 values over 16-lane subgroup (15 shuffles) ----
    // Invariant after step j: slot i of lane l holds sample
    //   i + sum_{j'<=j} bit_{j'}(l) * (8 >> j'), summed over lanes matched so far.
    // After 4 steps lane l slot 0 = sample brev4(l & 15) summed over its
    // 16-lane subgroup.
    const int l4 = r & 15;
    #pragma unroll
    for (int j = 0; j < 4; ++j) {
        const int m = 1 << j;
        const int h = 8 >> j;
        const bool hi = (l4 & m) != 0;
        #pragma unroll
        for (int i = 0; i < h; ++i) {
            const float send = hi ? acc[i] : acc[h + i];
            const float recv = __shfl_xor(send, m, 64);
            acc[i] = (hi ? acc[h + i] : acc[i]) + recv;
        }
    }
    // add the other 16-lane subgroup of this row (lane r <-> r^16, same sample)
    acc[0] += __shfl_xor(acc[0], 16, 64);

    if (r < 16) {
        const int s = ((r & 1) << 3) | ((r & 2) << 1) | ((r & 4) >> 1) | ((r & 8) >> 3);
        out[(size_t)b * NS + s] = acc[0];
    }
}

extern "C" void kernel_launch(void* const* d_in, const int* in_sizes, int n_in,
                              void* d_out, int out_size, void* d_ws, size_t ws_size,
                              hipStream_t stream) {
    const int*   doc_ids     = (const int*)d_in[0];
    const int*   context_ids = (const int*)d_in[1];
    const int*   sample_ids  = (const int*)d_in[2];
    const float* pm          = (const float*)d_in[3];
    const float* wm          = (const float*)d_in[4];
    const float* outputs     = (const float*)d_in[5];
    float*       out         = (float*)d_out;

    const size_t transposed_bytes = (size_t)N_WORDS * VEC_D * sizeof(float);

    if (ws_size >= transposed_bytes) {
        float* outT = (float*)d_ws;
        transpose_kernel<<<N_WORDS / 32, 256, 0, stream>>>(outputs, outT);
        dm_kernel<true><<<BATCH / 8, 256, 0, stream>>>(
            doc_ids, context_ids, sample_ids, pm, wm, outT, out);
    } else {
        dm_kernel<false><<<BATCH / 8, 256, 0, stream>>>(
            doc_ids, context_ids, sample_ids, pm, wm, outputs, out);
    }
}